// Round 5
// baseline (204.056 us; speedup 1.0000x reference)
//
#include <hip/hip_runtime.h>
#include <hip/hip_bf16.h>

// Problem constants (fixed by reference)
#define BB 32
#define DD 64
#define HWHW 4096
#define NPOS 131072
#define NELEM (NPOS * DD)          // 8388608
#define KK 512
#define LOSS_SCALE (1.2f / 8388608.f)
#define DELTA 2.0f                  // >= 2*eps(bf16 dot) with ~3x margin
#define QCAP 4096
#define PT 2                        // position-tiles per wave
#define POSB 128                    // positions per block (4 waves * PT * 16)
#define NBLK (NPOS / POSB)          // 1024 blocks = 4 blocks/CU

typedef __attribute__((ext_vector_type(8))) short short8v;   // 8 bf16
typedef __attribute__((ext_vector_type(4))) float float4v;   // MFMA acc

__device__ inline unsigned short f2bf(float f) {             // fp32->bf16 RNE
    unsigned u = __float_as_uint(f);
    unsigned r = u + 0x7FFFu + ((u >> 16) & 1u);
    return (unsigned short)(r >> 16);
}
__device__ inline float bf2f(unsigned short s) {
    return __uint_as_float(((unsigned)s) << 16);
}
__device__ inline unsigned f2o(float f) {                    // order-preserving f32->u32
    unsigned u = __float_as_uint(f);
    return ((int)u < 0) ? ~u : (u | 0x80000000u);
}

// ---------------------------------------------------------------------------
// Prep: E fp32 -> bf16 (RNE) into ws; ne2h[k] = -0.5*|e_k|^2 (negated -> MFMA
// C-operand and drain addend).
// ---------------------------------------------------------------------------
__global__ __launch_bounds__(256) void vq_prep(const float* __restrict__ emb,
                                               unsigned short* __restrict__ ebf,
                                               float* __restrict__ ne2h) {
    const int t = blockIdx.x * 256 + threadIdx.x;   // 0..8191
    const int row = t >> 4, c = t & 15;
    const float4 v = *(const float4*)(emb + row * DD + c * 4);
    unsigned u0 = (unsigned)f2bf(v.x) | ((unsigned)f2bf(v.y) << 16);
    unsigned u1 = (unsigned)f2bf(v.z) | ((unsigned)f2bf(v.w) << 16);
    *(uint2*)(ebf + row * DD + c * 4) = make_uint2(u0, u1);
    float p = v.x * v.x + v.y * v.y + v.z * v.z + v.w * v.w;
    p += __shfl_xor(p, 1, 64); p += __shfl_xor(p, 2, 64);
    p += __shfl_xor(p, 4, 64); p += __shfl_xor(p, 8, 64);
    if (c == 0) ne2h[row] = -0.5f * p;
}

// ---------------------------------------------------------------------------
// Main: block = 128 positions, 4 waves x 2 pos-tiles; grid 1024 (4 blocks/CU).
// NO min-wave forcing: R4's __launch_bounds__(256,4) caused scratch spills
// (WRITE 104 MB vs 33 ideal). Natural pressure here is ~70-90 VGPR.
// SINGLE fused pass: scores S^T = E_bf16 * X_bf16^T via mfma_f32_16x16x32_bf16
// with C = -e2/2; per ct-tile update the cross-lane running max M and enqueue
// codes with score >= M - DELTA. Since running M <= final M, the candidate set
// is a superset of {codes within DELTA of final max} -> true fp32 argmax is
// always enqueued (and the max itself always is). Drain: fp32 rescore,
// packed-key LDS atomicMax (monotone f32 | (511-k) => first-min-index ties).
//   A-frag (E): lane reads 16B at ebf[row=ct*16+(l&15)][(l>>4)*8 + h*32]
//   B-frag (X): elem j <-> d = h*32+(l>>4)*8+j (same k-map -> permutation
//   cancels). C/D: col=l&15=position, row=(l>>4)*4+r=code (m89).
// ---------------------------------------------------------------------------
__global__ __launch_bounds__(256) void vq_main(
        const float* __restrict__ feat,
        const float* __restrict__ emb,
        const unsigned short* __restrict__ ebf,
        const float* __restrict__ ne2h,
        float* __restrict__ out,
        float* __restrict__ loss) {

    __shared__ unsigned long long sbest[POSB];
    __shared__ unsigned qbuf[QCAP];
    __shared__ unsigned qcnt;
    __shared__ float wsum[4];

    const int tid = threadIdx.x;
    const int wid = tid >> 6, lane = tid & 63;
    const int l15 = lane & 15, lg = lane >> 4;

    if (tid < POSB) sbest[tid] = 0ull;
    if (tid == 0) qcnt = 0u;

    const int pbase = blockIdx.x * POSB;
    const int b     = pbase >> 12;
    const int hwb   = pbase & 4095;
    const float* featB = feat + (size_t)b * DD * HWHW;
    float*       outB  = out  + (size_t)b * DD * HWHW;
    const int wbase = wid * (PT * 16);   // 32 positions per wave

    // ---- build B-frags: x bf16 (RNE), PT pos-tiles x 2 k-halves ----
    // Per wave per d: 32 consecutive positions = one aligned 128B line.
    short8v bx[PT][2];
#pragma unroll
    for (int pt = 0; pt < PT; ++pt) {
        const int hw = hwb + wbase + pt * 16 + l15;
#pragma unroll
        for (int h = 0; h < 2; ++h) {
            float xv[8];
#pragma unroll
            for (int j = 0; j < 8; ++j) {
                const int d = h * 32 + lg * 8 + j;
                xv[j] = featB[(size_t)d * HWHW + hw];
            }
            short8v s;
#pragma unroll
            for (int j = 0; j < 8; ++j) s[j] = (short)f2bf(xv[j]);
            bx[pt][h] = s;
        }
    }

    __syncthreads();   // LDS init visible

    const char* ebfB = (const char*)ebf;

    // ---- single fused pass: max-track + candidate enqueue ----
    float M[PT];
#pragma unroll
    for (int pt = 0; pt < PT; ++pt) M[pt] = -3.0e38f;

    short8v a0n = *(const short8v*)(ebfB + l15 * 128 + lg * 16);
    short8v a1n = *(const short8v*)(ebfB + l15 * 128 + 64 + lg * 16);
    float4v ne2n = *(const float4v*)(ne2h + lg * 4);

    for (int ct = 0; ct < 32; ++ct) {
        const short8v a0c = a0n, a1c = a1n;
        const float4v ne2c = ne2n;
        if (ct < 31) {
            const char* p = ebfB + ((ct + 1) * 16 + l15) * 128 + lg * 16;
            a0n = *(const short8v*)p;
            a1n = *(const short8v*)(p + 64);
            ne2n = *(const float4v*)(ne2h + (ct + 1) * 16 + lg * 4);
        }
        float4v acc[PT];
#pragma unroll
        for (int pt = 0; pt < PT; ++pt)
            acc[pt] = __builtin_amdgcn_mfma_f32_16x16x32_bf16(a0c, bx[pt][0], ne2c, 0, 0, 0);
#pragma unroll
        for (int pt = 0; pt < PT; ++pt)
            acc[pt] = __builtin_amdgcn_mfma_f32_16x16x32_bf16(a1c, bx[pt][1], acc[pt], 0, 0, 0);
#pragma unroll
        for (int pt = 0; pt < PT; ++pt) {
            const float m01 = fmaxf(acc[pt][0], acc[pt][1]);
            const float m23 = fmaxf(acc[pt][2], acc[pt][3]);
            const float m4  = fmaxf(m01, m23);
            // cross-lane (per-position) running max: merge the 4 lg groups
            float mm = fmaxf(m4, __shfl_xor(m4, 16, 64));
            mm = fmaxf(mm, __shfl_xor(mm, 32, 64));
            M[pt] = fmaxf(M[pt], mm);
            const float thr = M[pt] - DELTA;
            if (m4 >= thr) {                 // rare; per-lane predicate
#pragma unroll
                for (int r = 0; r < 4; ++r) {
                    if (acc[pt][r] >= thr) {
                        const unsigned idx  = atomicAdd(&qcnt, 1u);
                        const unsigned code = (unsigned)(ct * 16 + lg * 4 + r);
                        const unsigned pos  = (unsigned)(wbase + pt * 16 + l15);
                        if (idx < QCAP) qbuf[idx] = (pos << 9) | code;
                    }
                }
            }
        }
    }

    __syncthreads();

    // ---- drain: fp32 rescore of candidates, resolve winner per position ----
    // Fallback (prob ~0): queue overflow -> rescore all (pos, code) pairs.
    const unsigned qn  = qcnt;
    const bool     ovf = (qn > (unsigned)QCAP);
    const unsigned n   = ovf ? (unsigned)(POSB * KK) : qn;
    for (unsigned i = tid; i < n; i += 256) {
        unsigned p, k;
        if (ovf) { p = i >> 9; k = i & 511u; }
        else     { const unsigned e = qbuf[i]; p = e >> 9; k = e & 511u; }
        const float4* er4 = (const float4*)(emb + k * DD);
        const float*  fp  = featB + hwb + p;
        float a0 = 0.f, a1 = 0.f;
#pragma unroll 4
        for (int dq = 0; dq < 16; ++dq) {
            const float4 e4 = er4[dq];
            a0 = fmaf(fp[(size_t)(4 * dq    ) * HWHW], e4.x, a0);
            a1 = fmaf(fp[(size_t)(4 * dq + 1) * HWHW], e4.y, a1);
            a0 = fmaf(fp[(size_t)(4 * dq + 2) * HWHW], e4.z, a0);
            a1 = fmaf(fp[(size_t)(4 * dq + 3) * HWHW], e4.w, a1);
        }
        const float sc = (a0 + a1) + ne2h[k];
        const unsigned long long key =
            ((unsigned long long)f2o(sc) << 32) | (unsigned long long)(511u - k);
        atomicMax(&sbest[p], key);   // ties -> larger (511-k) -> smaller k
    }

    __syncthreads();

    // ---- epilogue: st = e[k*] (exact), loss from in-register bf16 x ----
    float lsum = 0.f;
#pragma unroll
    for (int pt = 0; pt < PT; ++pt) {
        const int pl = wbase + pt * 16 + l15;
        const int hw = hwb + pl;
        const unsigned long long key = sbest[pl];
        const unsigned k = 511u - (unsigned)key;
        const float* er = emb + k * DD;
#pragma unroll
        for (int h = 0; h < 2; ++h) {
            const short8v xs = bx[pt][h];
#pragma unroll
            for (int jj = 0; jj < 2; ++jj) {
                const float4v ev = *(const float4v*)(er + h * 32 + lg * 8 + jj * 4);
#pragma unroll
                for (int c = 0; c < 4; ++c) {
                    const int j = jj * 4 + c;
                    const int d = h * 32 + lg * 8 + j;
                    const float q = ev[c];
                    outB[(size_t)d * HWHW + hw] = q;
                    const float diff = q - bf2f((unsigned short)xs[j]);
                    lsum = fmaf(diff, diff, lsum);
                }
            }
        }
    }

#pragma unroll
    for (int off = 32; off > 0; off >>= 1) lsum += __shfl_down(lsum, off, 64);
    if (lane == 0) wsum[wid] = lsum;
    __syncthreads();
    if (tid == 0)
        atomicAdd(loss, (wsum[0] + wsum[1] + wsum[2] + wsum[3]) * LOSS_SCALE);
}

// ---------------------------------------------------------------------------
extern "C" void kernel_launch(void* const* d_in, const int* in_sizes, int n_in,
                              void* d_out, int out_size, void* d_ws, size_t ws_size,
                              hipStream_t stream) {
    const float* feat = (const float*)d_in[0];   // (32,64,64,64) fp32
    const float* emb  = (const float*)d_in[1];   // (512,64) fp32
    float* out  = (float*)d_out;                 // [0..NELEM) = st, [NELEM] = loss
    float* loss = out + NELEM;

    unsigned short* ebf  = (unsigned short*)d_ws;                // 64 KiB bf16 codebook
    float*          ne2h = (float*)((char*)d_ws + 64 * 1024);    // 2 KiB, -|e|^2/2

    hipMemsetAsync(loss, 0, sizeof(float), stream);
    vq_prep<<<dim3(32), dim3(256), 0, stream>>>(emb, ebf, ne2h);
    vq_main<<<dim3(NBLK), dim3(256), 0, stream>>>(feat, emb, ebf, ne2h, out, loss);
}

// Round 6
// 173.906 us; speedup vs baseline: 1.1734x; 1.1734x over previous
//
#include <hip/hip_runtime.h>
#include <hip/hip_bf16.h>

// Problem constants (fixed by reference)
#define BB 32
#define DD 64
#define HWHW 4096
#define NPOS 131072
#define NELEM (NPOS * DD)          // 8388608
#define KK 512
#define LOSS_SCALE (1.2f / 8388608.f)
#define DELTA 2.0f                  // >= 2*eps(bf16 dot) with ~3x margin
#define QCAP 4096
#define PT 2                        // position-tiles per wave
#define POSB 128                    // positions per block (4 waves * PT * 16)
#define NBLK (NPOS / POSB)          // 1024 blocks = 4 blocks/CU

typedef __attribute__((ext_vector_type(8))) short short8v;   // 8 bf16
typedef __attribute__((ext_vector_type(4))) float float4v;   // MFMA acc

__device__ inline unsigned short f2bf(float f) {             // fp32->bf16 RNE
    unsigned u = __float_as_uint(f);
    unsigned r = u + 0x7FFFu + ((u >> 16) & 1u);
    return (unsigned short)(r >> 16);
}
__device__ inline float bf2f(unsigned short s) {
    return __uint_as_float(((unsigned)s) << 16);
}
__device__ inline unsigned f2o(float f) {                    // order-preserving f32->u32
    unsigned u = __float_as_uint(f);
    return ((int)u < 0) ? ~u : (u | 0x80000000u);
}

// ---------------------------------------------------------------------------
// Prep: E fp32 -> bf16 (RNE) into ws; ne2h[k] = -0.5*|e_k|^2 (negated -> MFMA
// C-operand and drain addend).
// ---------------------------------------------------------------------------
__global__ __launch_bounds__(256) void vq_prep(const float* __restrict__ emb,
                                               unsigned short* __restrict__ ebf,
                                               float* __restrict__ ne2h) {
    const int t = blockIdx.x * 256 + threadIdx.x;   // 0..8191
    const int row = t >> 4, c = t & 15;
    const float4 v = *(const float4*)(emb + row * DD + c * 4);
    unsigned u0 = (unsigned)f2bf(v.x) | ((unsigned)f2bf(v.y) << 16);
    unsigned u1 = (unsigned)f2bf(v.z) | ((unsigned)f2bf(v.w) << 16);
    *(uint2*)(ebf + row * DD + c * 4) = make_uint2(u0, u1);
    float p = v.x * v.x + v.y * v.y + v.z * v.z + v.w * v.w;
    p += __shfl_xor(p, 1, 64); p += __shfl_xor(p, 2, 64);
    p += __shfl_xor(p, 4, 64); p += __shfl_xor(p, 8, 64);
    if (c == 0) ne2h[row] = -0.5f * p;
}

// ---------------------------------------------------------------------------
// Main. R3's two-pass structure (branch-free pass 1; end-of-pass shuffles
// ONLY — R5's in-loop shfl/atomic chain was the regression) at 4 blocks/CU
// (R3 ran 1 wave/SIMD = 93% stall) with no launch-bounds cap (R4's cap
// spilled: WRITE 104 MB).
// Scores S^T = E_bf16 * X_bf16^T via mfma_f32_16x16x32_bf16, C = -e2/2.
//   A-frag (E): lane reads 16B at ebf[row=ct*16+(l&15)][(l>>4)*8 + h*32]
//   B-frag (X): elem j <-> d = h*32+(l>>4)*8+j (same k-map as A -> internal
//   permutation cancels). C/D: col=l&15=position, row=(l>>4)*4+r=code (m89).
// Pass1: per-position max score. Pass2: bitwise-identical recompute, enqueue
// codes within DELTA of max. Drain: fp32 rescore, packed-key LDS atomicMax
// (monotone f32 | (511-k) => first-min-index ties). Both validated R3-R5.
// ---------------------------------------------------------------------------
__global__ __launch_bounds__(256) void vq_main(
        const float* __restrict__ feat,
        const float* __restrict__ emb,
        const unsigned short* __restrict__ ebf,
        const float* __restrict__ ne2h,
        float* __restrict__ out,
        float* __restrict__ loss) {

    __shared__ unsigned long long sbest[POSB];
    __shared__ unsigned qbuf[QCAP];
    __shared__ unsigned qcnt;
    __shared__ float wsum[4];

    const int tid = threadIdx.x;
    const int wid = tid >> 6, lane = tid & 63;
    const int l15 = lane & 15, lg = lane >> 4;

    if (tid < POSB) sbest[tid] = 0ull;
    if (tid == 0) qcnt = 0u;

    const int pbase = blockIdx.x * POSB;
    const int b     = pbase >> 12;
    const int hwb   = pbase & 4095;
    const float* featB = feat + (size_t)b * DD * HWHW;
    float*       outB  = out  + (size_t)b * DD * HWHW;
    const int wbase = wid * (PT * 16);   // 32 positions per wave

    // ---- staging: hoist ALL 32 feat loads into one independent batch ----
    float xv[PT][2][8];
#pragma unroll
    for (int pt = 0; pt < PT; ++pt) {
        const int hw = hwb + wbase + pt * 16 + l15;
#pragma unroll
        for (int h = 0; h < 2; ++h)
#pragma unroll
            for (int j = 0; j < 8; ++j)
                xv[pt][h][j] = featB[(size_t)(h * 32 + lg * 8 + j) * HWHW + hw];
    }
    short8v bx[PT][2];
#pragma unroll
    for (int pt = 0; pt < PT; ++pt)
#pragma unroll
        for (int h = 0; h < 2; ++h) {
            short8v s;
#pragma unroll
            for (int j = 0; j < 8; ++j) s[j] = (short)f2bf(xv[pt][h][j]);
            bx[pt][h] = s;
        }

    __syncthreads();   // LDS init visible

    const char* ebfB = (const char*)ebf;

    // ---- pass 1: branch-free per-position max score ----
    float M[PT];
#pragma unroll
    for (int pt = 0; pt < PT; ++pt) M[pt] = -3.0e38f;

    short8v a0n = *(const short8v*)(ebfB + l15 * 128 + lg * 16);
    short8v a1n = *(const short8v*)(ebfB + l15 * 128 + 64 + lg * 16);
    float4v ne2n = *(const float4v*)(ne2h + lg * 4);

    for (int ct = 0; ct < 32; ++ct) {
        const short8v a0c = a0n, a1c = a1n;
        const float4v ne2c = ne2n;
        if (ct < 31) {
            const char* p = ebfB + ((ct + 1) * 16 + l15) * 128 + lg * 16;
            a0n = *(const short8v*)p;
            a1n = *(const short8v*)(p + 64);
            ne2n = *(const float4v*)(ne2h + (ct + 1) * 16 + lg * 4);
        }
        float4v acc[PT];
#pragma unroll
        for (int pt = 0; pt < PT; ++pt)
            acc[pt] = __builtin_amdgcn_mfma_f32_16x16x32_bf16(a0c, bx[pt][0], ne2c, 0, 0, 0);
#pragma unroll
        for (int pt = 0; pt < PT; ++pt)
            acc[pt] = __builtin_amdgcn_mfma_f32_16x16x32_bf16(a1c, bx[pt][1], acc[pt], 0, 0, 0);
#pragma unroll
        for (int pt = 0; pt < PT; ++pt) {
            const float m01 = fmaxf(acc[pt][0], acc[pt][1]);
            const float m23 = fmaxf(acc[pt][2], acc[pt][3]);
            M[pt] = fmaxf(M[pt], fmaxf(m01, m23));
        }
    }

    // ---- merge across the 4 lanes holding the same position column ----
    float thr[PT];
#pragma unroll
    for (int pt = 0; pt < PT; ++pt) {
        float m = M[pt];
        m = fmaxf(m, __shfl_xor(m, 16, 64));
        m = fmaxf(m, __shfl_xor(m, 32, 64));
        thr[pt] = m - DELTA;
    }

    // ---- pass 2: bitwise-identical recompute, enqueue candidates ----
    a0n = *(const short8v*)(ebfB + l15 * 128 + lg * 16);
    a1n = *(const short8v*)(ebfB + l15 * 128 + 64 + lg * 16);
    ne2n = *(const float4v*)(ne2h + lg * 4);

    for (int ct = 0; ct < 32; ++ct) {
        const short8v a0c = a0n, a1c = a1n;
        const float4v ne2c = ne2n;
        if (ct < 31) {
            const char* p = ebfB + ((ct + 1) * 16 + l15) * 128 + lg * 16;
            a0n = *(const short8v*)p;
            a1n = *(const short8v*)(p + 64);
            ne2n = *(const float4v*)(ne2h + (ct + 1) * 16 + lg * 4);
        }
        float4v acc[PT];
#pragma unroll
        for (int pt = 0; pt < PT; ++pt)
            acc[pt] = __builtin_amdgcn_mfma_f32_16x16x32_bf16(a0c, bx[pt][0], ne2c, 0, 0, 0);
#pragma unroll
        for (int pt = 0; pt < PT; ++pt)
            acc[pt] = __builtin_amdgcn_mfma_f32_16x16x32_bf16(a1c, bx[pt][1], acc[pt], 0, 0, 0);
#pragma unroll
        for (int pt = 0; pt < PT; ++pt) {
            const float m01 = fmaxf(acc[pt][0], acc[pt][1]);
            const float m23 = fmaxf(acc[pt][2], acc[pt][3]);
            const float mx  = fmaxf(m01, m23);
            if (__any(mx >= thr[pt])) {
#pragma unroll
                for (int r = 0; r < 4; ++r) {
                    if (acc[pt][r] >= thr[pt]) {
                        const unsigned idx  = atomicAdd(&qcnt, 1u);
                        const unsigned code = (unsigned)(ct * 16 + lg * 4 + r);
                        const unsigned pos  = (unsigned)(wbase + pt * 16 + l15);
                        if (idx < QCAP) qbuf[idx] = (pos << 9) | code;
                    }
                }
            }
        }
    }

    __syncthreads();

    // ---- drain: fp32 rescore of candidates, resolve winner per position ----
    // Fallback (prob ~0): queue overflow -> rescore all (pos, code) pairs.
    const unsigned qn  = qcnt;
    const bool     ovf = (qn > (unsigned)QCAP);
    const unsigned n   = ovf ? (unsigned)(POSB * KK) : qn;
    for (unsigned i = tid; i < n; i += 256) {
        unsigned p, k;
        if (ovf) { p = i >> 9; k = i & 511u; }
        else     { const unsigned e = qbuf[i]; p = e >> 9; k = e & 511u; }
        const float4* er4 = (const float4*)(emb + k * DD);
        const float*  fp  = featB + hwb + p;
        float a0 = 0.f, a1 = 0.f;
#pragma unroll 4
        for (int dq = 0; dq < 16; ++dq) {
            const float4 e4 = er4[dq];
            a0 = fmaf(fp[(size_t)(4 * dq    ) * HWHW], e4.x, a0);
            a1 = fmaf(fp[(size_t)(4 * dq + 1) * HWHW], e4.y, a1);
            a0 = fmaf(fp[(size_t)(4 * dq + 2) * HWHW], e4.z, a0);
            a1 = fmaf(fp[(size_t)(4 * dq + 3) * HWHW], e4.w, a1);
        }
        const float sc = (a0 + a1) + ne2h[k];
        const unsigned long long key =
            ((unsigned long long)f2o(sc) << 32) | (unsigned long long)(511u - k);
        atomicMax(&sbest[p], key);   // ties -> larger (511-k) -> smaller k
    }

    __syncthreads();

    // ---- epilogue: st = e[k*] (exact), loss from in-register bf16 x ----
    float lsum = 0.f;
#pragma unroll
    for (int pt = 0; pt < PT; ++pt) {
        const int pl = wbase + pt * 16 + l15;
        const int hw = hwb + pl;
        const unsigned long long key = sbest[pl];
        const unsigned k = 511u - (unsigned)key;
        const float* er = emb + k * DD;
#pragma unroll
        for (int h = 0; h < 2; ++h) {
            const short8v xs = bx[pt][h];
#pragma unroll
            for (int jj = 0; jj < 2; ++jj) {
                const float4v ev = *(const float4v*)(er + h * 32 + lg * 8 + jj * 4);
#pragma unroll
                for (int c = 0; c < 4; ++c) {
                    const int j = jj * 4 + c;
                    const int d = h * 32 + lg * 8 + j;
                    const float q = ev[c];
                    outB[(size_t)d * HWHW + hw] = q;
                    const float diff = q - bf2f((unsigned short)xs[j]);
                    lsum = fmaf(diff, diff, lsum);
                }
            }
        }
    }

#pragma unroll
    for (int off = 32; off > 0; off >>= 1) lsum += __shfl_down(lsum, off, 64);
    if (lane == 0) wsum[wid] = lsum;
    __syncthreads();
    if (tid == 0)
        atomicAdd(loss, (wsum[0] + wsum[1] + wsum[2] + wsum[3]) * LOSS_SCALE);
}

// ---------------------------------------------------------------------------
extern "C" void kernel_launch(void* const* d_in, const int* in_sizes, int n_in,
                              void* d_out, int out_size, void* d_ws, size_t ws_size,
                              hipStream_t stream) {
    const float* feat = (const float*)d_in[0];   // (32,64,64,64) fp32
    const float* emb  = (const float*)d_in[1];   // (512,64) fp32
    float* out  = (float*)d_out;                 // [0..NELEM) = st, [NELEM] = loss
    float* loss = out + NELEM;

    unsigned short* ebf  = (unsigned short*)d_ws;                // 64 KiB bf16 codebook
    float*          ne2h = (float*)((char*)d_ws + 64 * 1024);    // 2 KiB, -|e|^2/2

    hipMemsetAsync(loss, 0, sizeof(float), stream);
    vq_prep<<<dim3(32), dim3(256), 0, stream>>>(emb, ebf, ne2h);
    vq_main<<<dim3(NBLK), dim3(256), 0, stream>>>(feat, emb, ebf, ne2h, out, loss);
}

// Round 8
// 135.046 us; speedup vs baseline: 1.5110x; 1.2878x over previous
//
#include <hip/hip_runtime.h>
#include <hip/hip_bf16.h>

// Problem constants (fixed by reference)
#define BB 32
#define DD 64
#define HWHW 4096
#define NPOS 131072
#define NELEM (NPOS * DD)          // 8388608
#define KK 512
#define LOSS_SCALE (1.2f / 8388608.f)
#define DELTA 2.0f                  // >= 2*eps(bf16 dot) with ~3x margin
#define QCAP 4096
#define PT 2                        // position-tiles per wave
#define NTHR 1024                   // 16 waves
#define POSB 512                    // positions per block (16 waves * PT * 16)
#define NBLK (NPOS / POSB)          // 256 blocks = exactly 1 per CU

typedef __attribute__((ext_vector_type(8))) short short8v;   // 8 bf16
typedef __attribute__((ext_vector_type(4))) float float4v;   // MFMA acc

__device__ inline unsigned short f2bf(float f) {             // fp32->bf16 RNE
    unsigned u = __float_as_uint(f);
    unsigned r = u + 0x7FFFu + ((u >> 16) & 1u);
    return (unsigned short)(r >> 16);
}
__device__ inline float bf2f(unsigned short s) {
    return __uint_as_float(((unsigned)s) << 16);
}
__device__ inline unsigned f2o(float f) {                    // order-preserving f32->u32
    unsigned u = __float_as_uint(f);
    return ((int)u < 0) ? ~u : (u | 0x80000000u);
}

// ---------------------------------------------------------------------------
// Prep: E fp32 -> bf16 (RNE) into ws; ne2h[k] = -0.5*|e_k|^2 (negated -> MFMA
// C-operand and drain addend).
// ---------------------------------------------------------------------------
__global__ __launch_bounds__(256) void vq_prep(const float* __restrict__ emb,
                                               unsigned short* __restrict__ ebf,
                                               float* __restrict__ ne2h) {
    const int t = blockIdx.x * 256 + threadIdx.x;   // 0..8191
    const int row = t >> 4, c = t & 15;
    const float4 v = *(const float4*)(emb + row * DD + c * 4);
    unsigned u0 = (unsigned)f2bf(v.x) | ((unsigned)f2bf(v.y) << 16);
    unsigned u1 = (unsigned)f2bf(v.z) | ((unsigned)f2bf(v.w) << 16);
    *(uint2*)(ebf + row * DD + c * 4) = make_uint2(u0, u1);
    float p = v.x * v.x + v.y * v.y + v.z * v.z + v.w * v.w;
    p += __shfl_xor(p, 1, 64); p += __shfl_xor(p, 2, 64);
    p += __shfl_xor(p, 4, 64); p += __shfl_xor(p, 8, 64);
    if (c == 0) ne2h[row] = -0.5f * p;
}

// ---------------------------------------------------------------------------
// Main. R6 structure (two-pass, branch-free pass 1, fp32 drain) with the
// codebook staged in LDS (R6 diagnosis: 64 KiB codebook thrashes 32 KiB L1,
// every A-frag load was an L2 round-trip at only ~60 cyc covering compute).
// 1024-thread block, grid 256 = 1 block/CU -> deterministic 4 waves/SIMD.
// LDS layout: chunk c (16B) of codebook row r stored at slot (c ^ (r&7)) ->
// a wave's 64 ds_read_b128 spread uniformly over all 8 bank groups (8
// lanes/group = BW minimum, conflict-free). Same XOR on write and read.
// Scores S^T = E_bf16 * X_bf16^T via mfma_f32_16x16x32_bf16, C = -e2/2.
//   A-frag (E): row=ct*16+(l&15), chunks lg (k-half 0) / lg|4 (k-half 1)
//   B-frag (X): elem j <-> d = h*32+(l>>4)*8+j (same k-map as A -> internal
//   permutation cancels). C/D: col=l&15=position, row=(l>>4)*4+r=code (m89).
// Pass1: per-position max score. Pass2: bitwise-identical recompute, enqueue
// codes within DELTA of max. Drain: fp32 rescore, packed-key LDS atomicMax
// (monotone f32 | (511-k) => first-min-index ties). Validated R3-R6.
// ---------------------------------------------------------------------------
__global__ __launch_bounds__(NTHR) void vq_main(
        const float* __restrict__ feat,
        const float* __restrict__ emb,
        const unsigned short* __restrict__ ebf,
        const float* __restrict__ ne2h,
        float* __restrict__ out,
        float* __restrict__ loss) {

    __shared__ uint4 ebf_lds[4096];          // 64 KiB swizzled bf16 codebook
    __shared__ float ne2_lds[KK];            // 2 KiB
    __shared__ unsigned long long sbest[POSB];
    __shared__ unsigned qbuf[QCAP];
    __shared__ unsigned qcnt;
    __shared__ float wsum[NTHR / 64];

    const int tid = threadIdx.x;
    const int wid = tid >> 6, lane = tid & 63;
    const int l15 = lane & 15, lg = lane >> 4;

    // ---- stage codebook into LDS (swizzled) + init ----
    {
        const uint4* src = (const uint4*)ebf;    // 4096 16B chunks
#pragma unroll
        for (int i = 0; i < 4; ++i) {
            const int idx = tid * 4 + i;         // chunk index
            const int row = idx >> 3, c = idx & 7;
            ebf_lds[row * 8 + (c ^ (row & 7))] = src[idx];
        }
    }
    if (tid < KK) ne2_lds[tid] = ne2h[tid];
    if (tid < POSB) sbest[tid] = 0ull;
    if (tid == 0) qcnt = 0u;

    const int pbase = blockIdx.x * POSB;
    const int b     = pbase >> 12;
    const int hwb   = pbase & 4095;
    const float* featB = feat + (size_t)b * DD * HWHW;
    float*       outB  = out  + (size_t)b * DD * HWHW;
    const int wbase = wid * (PT * 16);   // 32 positions per wave

    // ---- staging X: hoist all 32 feat loads, convert to bf16 B-frags ----
    float xv[PT][2][8];
#pragma unroll
    for (int pt = 0; pt < PT; ++pt) {
        const int hw = hwb + wbase + pt * 16 + l15;
#pragma unroll
        for (int h = 0; h < 2; ++h)
#pragma unroll
            for (int j = 0; j < 8; ++j)
                xv[pt][h][j] = featB[(size_t)(h * 32 + lg * 8 + j) * HWHW + hw];
    }
    short8v bx[PT][2];
#pragma unroll
    for (int pt = 0; pt < PT; ++pt)
#pragma unroll
        for (int h = 0; h < 2; ++h) {
            short8v s;
#pragma unroll
            for (int j = 0; j < 8; ++j) s[j] = (short)f2bf(xv[pt][h][j]);
            bx[pt][h] = s;
        }

    __syncthreads();   // codebook + init visible

    // per-lane swizzled LDS base slots (constant across ct: ct*16 ≡ 0 mod 8)
    const int swz = l15 & 7;
    const uint4* a0p = &ebf_lds[l15 * 8 + (lg ^ swz)];
    const uint4* a1p = &ebf_lds[l15 * 8 + ((lg | 4) ^ swz)];

    // ---- pass 1: branch-free per-position max score ----
    float M[PT];
#pragma unroll
    for (int pt = 0; pt < PT; ++pt) M[pt] = -3.0e38f;

    short8v a0n = *(const short8v*)a0p;
    short8v a1n = *(const short8v*)a1p;
    float4v ne2n = *(const float4v*)&ne2_lds[lg * 4];

    for (int ct = 0; ct < 32; ++ct) {
        const short8v a0c = a0n, a1c = a1n;
        const float4v ne2c = ne2n;
        if (ct < 31) {
            a0n = *(const short8v*)(a0p + (ct + 1) * 128);
            a1n = *(const short8v*)(a1p + (ct + 1) * 128);
            ne2n = *(const float4v*)&ne2_lds[(ct + 1) * 16 + lg * 4];
        }
        float4v acc[PT];
#pragma unroll
        for (int pt = 0; pt < PT; ++pt)
            acc[pt] = __builtin_amdgcn_mfma_f32_16x16x32_bf16(a0c, bx[pt][0], ne2c, 0, 0, 0);
#pragma unroll
        for (int pt = 0; pt < PT; ++pt)
            acc[pt] = __builtin_amdgcn_mfma_f32_16x16x32_bf16(a1c, bx[pt][1], acc[pt], 0, 0, 0);
#pragma unroll
        for (int pt = 0; pt < PT; ++pt) {
            const float m01 = fmaxf(acc[pt][0], acc[pt][1]);
            const float m23 = fmaxf(acc[pt][2], acc[pt][3]);
            M[pt] = fmaxf(M[pt], fmaxf(m01, m23));
        }
    }

    // ---- merge across the 4 lanes holding the same position column ----
    float thr[PT];
#pragma unroll
    for (int pt = 0; pt < PT; ++pt) {
        float m = M[pt];
        m = fmaxf(m, __shfl_xor(m, 16, 64));
        m = fmaxf(m, __shfl_xor(m, 32, 64));
        thr[pt] = m - DELTA;
    }

    // ---- pass 2: bitwise-identical recompute, enqueue candidates ----
    a0n = *(const short8v*)a0p;
    a1n = *(const short8v*)a1p;
    ne2n = *(const float4v*)&ne2_lds[lg * 4];

    for (int ct = 0; ct < 32; ++ct) {
        const short8v a0c = a0n, a1c = a1n;
        const float4v ne2c = ne2n;
        if (ct < 31) {
            a0n = *(const short8v*)(a0p + (ct + 1) * 128);
            a1n = *(const short8v*)(a1p + (ct + 1) * 128);
            ne2n = *(const float4v*)&ne2_lds[(ct + 1) * 16 + lg * 4];
        }
        float4v acc[PT];
#pragma unroll
        for (int pt = 0; pt < PT; ++pt)
            acc[pt] = __builtin_amdgcn_mfma_f32_16x16x32_bf16(a0c, bx[pt][0], ne2c, 0, 0, 0);
#pragma unroll
        for (int pt = 0; pt < PT; ++pt)
            acc[pt] = __builtin_amdgcn_mfma_f32_16x16x32_bf16(a1c, bx[pt][1], acc[pt], 0, 0, 0);
#pragma unroll
        for (int pt = 0; pt < PT; ++pt) {
            const float m01 = fmaxf(acc[pt][0], acc[pt][1]);
            const float m23 = fmaxf(acc[pt][2], acc[pt][3]);
            const float mx  = fmaxf(m01, m23);
            if (__any(mx >= thr[pt])) {
#pragma unroll
                for (int r = 0; r < 4; ++r) {
                    if (acc[pt][r] >= thr[pt]) {
                        const unsigned idx  = atomicAdd(&qcnt, 1u);
                        const unsigned code = (unsigned)(ct * 16 + lg * 4 + r);
                        const unsigned pos  = (unsigned)(wbase + pt * 16 + l15);
                        if (idx < QCAP) qbuf[idx] = (pos << 9) | code;
                    }
                }
            }
        }
    }

    __syncthreads();

    // ---- drain: fp32 rescore of candidates, resolve winner per position ----
    // Fallback (prob ~0): queue overflow -> rescore all (pos, code) pairs.
    const unsigned qn  = qcnt;
    const bool     ovf = (qn > (unsigned)QCAP);
    const unsigned n   = ovf ? (unsigned)(POSB * KK) : qn;
    for (unsigned i = tid; i < n; i += NTHR) {
        unsigned p, k;
        if (ovf) { p = i >> 9; k = i & 511u; }
        else     { const unsigned e = qbuf[i]; p = e >> 9; k = e & 511u; }
        const float4* er4 = (const float4*)(emb + k * DD);
        const float*  fp  = featB + hwb + p;
        float a0 = 0.f, a1 = 0.f;
#pragma unroll 4
        for (int dq = 0; dq < 16; ++dq) {
            const float4 e4 = er4[dq];
            a0 = fmaf(fp[(size_t)(4 * dq    ) * HWHW], e4.x, a0);
            a1 = fmaf(fp[(size_t)(4 * dq + 1) * HWHW], e4.y, a1);
            a0 = fmaf(fp[(size_t)(4 * dq + 2) * HWHW], e4.z, a0);
            a1 = fmaf(fp[(size_t)(4 * dq + 3) * HWHW], e4.w, a1);
        }
        const float sc = (a0 + a1) + ne2h[k];
        const unsigned long long key =
            ((unsigned long long)f2o(sc) << 32) | (unsigned long long)(511u - k);
        atomicMax(&sbest[p], key);   // ties -> larger (511-k) -> smaller k
    }

    __syncthreads();

    // ---- epilogue: st = e[k*] (exact), loss from in-register bf16 x ----
    float lsum = 0.f;
#pragma unroll
    for (int pt = 0; pt < PT; ++pt) {
        const int pl = wbase + pt * 16 + l15;
        const int hw = hwb + pl;
        const unsigned long long key = sbest[pl];
        const unsigned k = 511u - (unsigned)key;
        const float* er = emb + k * DD;
#pragma unroll
        for (int h = 0; h < 2; ++h) {
            const short8v xs = bx[pt][h];
#pragma unroll
            for (int jj = 0; jj < 2; ++jj) {
                const float4v ev = *(const float4v*)(er + h * 32 + lg * 8 + jj * 4);
#pragma unroll
                for (int c = 0; c < 4; ++c) {
                    const int j = jj * 4 + c;
                    const int d = h * 32 + lg * 8 + j;
                    const float q = ev[c];
                    outB[(size_t)d * HWHW + hw] = q;
                    const float diff = q - bf2f((unsigned short)xs[j]);
                    lsum = fmaf(diff, diff, lsum);
                }
            }
        }
    }

#pragma unroll
    for (int off = 32; off > 0; off >>= 1) lsum += __shfl_down(lsum, off, 64);
    if (lane == 0) wsum[wid] = lsum;
    __syncthreads();
    if (tid == 0) {
        float s = 0.f;
#pragma unroll
        for (int w = 0; w < NTHR / 64; ++w) s += wsum[w];
        atomicAdd(loss, s * LOSS_SCALE);
    }
}

// ---------------------------------------------------------------------------
extern "C" void kernel_launch(void* const* d_in, const int* in_sizes, int n_in,
                              void* d_out, int out_size, void* d_ws, size_t ws_size,
                              hipStream_t stream) {
    const float* feat = (const float*)d_in[0];   // (32,64,64,64) fp32
    const float* emb  = (const float*)d_in[1];   // (512,64) fp32
    float* out  = (float*)d_out;                 // [0..NELEM) = st, [NELEM] = loss
    float* loss = out + NELEM;

    unsigned short* ebf  = (unsigned short*)d_ws;                // 64 KiB bf16 codebook
    float*          ne2h = (float*)((char*)d_ws + 64 * 1024);    // 2 KiB, -|e|^2/2

    hipMemsetAsync(loss, 0, sizeof(float), stream);
    vq_prep<<<dim3(32), dim3(256), 0, stream>>>(emb, ebf, ne2h);
    vq_main<<<dim3(NBLK), dim3(NTHR), 0, stream>>>(feat, emb, ebf, ne2h, out, loss);
}